// Round 9
// baseline (243.946 us; speedup 1.0000x reference)
//
#include <hip/hip_runtime.h>

// HyperConv: y[b,o,t] = sum_{i<3} sum_{c<16} x[b,c,t+8-4i] * w_b[i*16+c][o]
// w_b = LeakyReLU(p[b]@W1 + b1) @ W2 + b2, reshaped [48][16].
//
// R9: L3 write-allocate theory. FETCH_SIZE = 68 MB in EVERY round, but x
// (134 MB) is read exactly once => half of x is L3-resident, half evicted.
// x + write-allocated y = 265 MB > 256 MB L3 => steady-state thrash.
// __builtin_nontemporal_store demonstrably did NOT stop L3 allocation
// (FETCH identical with/without nt). Single-lever change on R8's clean
// zero-barrier structure: stores via inline-asm global_store_dwordx4 with
// sc0 sc1 nt (system-scope + non-temporal = no-allocate at all levels).
// Predict FETCH 68 -> <=15 MB, dur 87 -> 60-70 us if theory holds.
// Sentinels: VGPR<=128, WRITE~131MB.

#define NB 32
#define IN_CH 16
#define OUT_CH 16
#define KW 3
#define COND 8
#define T_OUT 65536
#define PADT 8
#define XT (T_OUT + PADT)            // 65544 floats, row stride of x
#define W2COLS (IN_CH * OUT_CH * KW) // 768
#define TPB 256
#define TPT 4                        // t-positions per thread
#define T_PER_BLOCK (TPB * TPT)      // 1024
#define T_PER_WAVE 256               // wave-private t-span
#define BLOCKS_PER_B (T_OUT / T_PER_BLOCK) // 64
#define WROW (T_PER_WAVE + PADT)     // 264 floats per wave-private row

typedef const __attribute__((address_space(1))) void* gvp;
typedef __attribute__((address_space(3))) void* svp;
typedef float f32x4 __attribute__((ext_vector_type(4)));

// Stage one wave-private 264-float row: main op = 64 lanes x 16 B (1 KB),
// halo op = lanes 0..1 x 16 B (32 B at +1024 B). Lanes 0,1 exist in every
// wave so both ops always issue: exactly 2 vmcnt ops/row/wave.
__device__ __forceinline__ void stage_wrow(const float* __restrict__ g,
                                           float* l, int lane)
{
    __builtin_amdgcn_global_load_lds((gvp)(g + lane * 4), (svp)l, 16, 0, 0);
    if (lane < 2)
        __builtin_amdgcn_global_load_lds((gvp)(g + T_PER_WAVE + lane * 4),
                                         (svp)(l + T_PER_WAVE), 16, 0, 0);
}

// One channel-row: 3 taps x 16 outputs x 4 t = 192 FMA/thread.
// xrow is the wave's private row; lane l reads floats [4l, 4l+11].
__device__ __forceinline__ void compute_row(const float* __restrict__ xrow,
                                            const float* __restrict__ w_lds,
                                            int c, float4* acc, int lane)
{
    const float4 l0 = *(const float4*)(xrow + lane * 4);      // tap i=2 (+0)
    const float4 l1 = *(const float4*)(xrow + lane * 4 + 4);  // tap i=1 (+4)
    const float4 l2 = *(const float4*)(xrow + lane * 4 + 8);  // tap i=0 (+8)
    const float4 vs[KW] = {l2, l1, l0};                       // vs[i]: offset 8-4i
#pragma unroll
    for (int i = 0; i < KW; ++i) {
        const float4 v = vs[i];
        const float* wrow = w_lds + (i * IN_CH + c) * OUT_CH;
#pragma unroll
        for (int og = 0; og < 4; ++og) {
            const float4 wv = *(const float4*)(wrow + og * 4);
            float4* a = acc + og * 4;
            a[0].x += v.x * wv.x; a[0].y += v.y * wv.x;
            a[0].z += v.z * wv.x; a[0].w += v.w * wv.x;
            a[1].x += v.x * wv.y; a[1].y += v.y * wv.y;
            a[1].z += v.z * wv.y; a[1].w += v.w * wv.y;
            a[2].x += v.x * wv.z; a[2].y += v.y * wv.z;
            a[2].z += v.z * wv.z; a[2].w += v.w * wv.z;
            a[3].x += v.x * wv.w; a[3].y += v.y * wv.w;
            a[3].z += v.z * wv.w; a[3].w += v.w * wv.w;
        }
    }
}

__global__ __launch_bounds__(TPB)
void hyperconv_kernel(const float* __restrict__ x,
                      const float* __restrict__ p,
                      const float* __restrict__ W1,
                      const float* __restrict__ b1,
                      const float* __restrict__ W2,
                      const float* __restrict__ b2,
                      float* __restrict__ y)
{
    __shared__ __align__(16) float xr[4][IN_CH][WROW]; // 66 KiB, wave-private rows
    __shared__ float h_lds[IN_CH];
    __shared__ __align__(16) float w_lds[W2COLS];      // 3 KiB

    const int tid    = threadIdx.x;
    const int wid    = tid >> 6;
    const int lane   = tid & 63;
    const int b      = blockIdx.x / BLOCKS_PER_B;
    const int tchunk = blockIdx.x % BLOCKS_PER_B;
    const int t0b    = tchunk * T_PER_BLOCK;

    // ---- hypernetwork FIRST (its global loads + full drain leave a clean
    //      vmem queue for the stage burst) ----
    if (tid < IN_CH) {
        float acc = b1[tid];
#pragma unroll
        for (int j = 0; j < COND; ++j)
            acc += p[b * COND + j] * W1[j * IN_CH + tid];
        h_lds[tid] = acc > 0.f ? acc : 0.2f * acc;
    }
    __syncthreads();

    // ---- w = h @ W2 + b2 : 768 entries, 3 per thread ----
#pragma unroll
    for (int r = 0; r < 3; ++r) {
        const int n = tid * 3 + r;
        float acc = b2[n];
#pragma unroll
        for (int c = 0; c < IN_CH; ++c)
            acc += h_lds[c] * W2[c * W2COLS + n];
        w_lds[n] = acc;
    }
    __syncthreads();   // drains vmcnt(0)+lgkmcnt(0): w_lds visible, queue clean

    // ---- stage burst: ALL 16 wave-private rows, 32 ops, ~17 KB in flight ----
    const float* xwb = x + (size_t)b * IN_CH * XT + t0b + wid * T_PER_WAVE;
#pragma unroll
    for (int c = 0; c < IN_CH; ++c)
        stage_wrow(xwb + c * XT, &xr[wid][c][0], lane);
    __builtin_amdgcn_sched_barrier(0);

    float4 acc[OUT_CH];
#pragma unroll
    for (int o = 0; o < OUT_CH; ++o) acc[o] = make_float4(0.f, 0.f, 0.f, 0.f);

    // ---- drain ladder: row r ready when its 2 ops (positions 2r,2r+1 in the
    // wave's in-order queue) complete => allow 32-2(r+1) = 30-2r younger ops.
    // No barriers: rows are wave-private; ds_read ordering vs DMA is enforced
    // by the asm memory clobber + program order.
#define STEP(R, V) \
    asm volatile("s_waitcnt vmcnt(" #V ")" ::: "memory"); \
    compute_row(&xr[wid][R][0], w_lds, R, acc, lane);
    STEP(0, 30)  STEP(1, 28)  STEP(2, 26)  STEP(3, 24)
    STEP(4, 22)  STEP(5, 20)  STEP(6, 18)  STEP(7, 16)
    STEP(8, 14)  STEP(9, 12)  STEP(10, 10) STEP(11, 8)
    STEP(12, 6)  STEP(13, 4)  STEP(14, 2)  STEP(15, 0)
#undef STEP

    // ---- store: system-scope non-temporal (sc0 sc1 nt) => no L3 allocate,
    //      so the 131 MB y stream stops evicting x from Infinity Cache ----
    float* yb = y + (size_t)b * OUT_CH * T_OUT + t0b + wid * T_PER_WAVE + lane * TPT;
#pragma unroll
    for (int o = 0; o < OUT_CH; ++o) {
        const float4 a = acc[o];
        f32x4 v = {a.x, a.y, a.z, a.w};
        asm volatile("global_store_dwordx4 %0, %1, off sc0 sc1 nt"
                     :: "v"(yb + o * T_OUT), "v"(v) : "memory");
    }
}

extern "C" void kernel_launch(void* const* d_in, const int* in_sizes, int n_in,
                              void* d_out, int out_size, void* d_ws, size_t ws_size,
                              hipStream_t stream) {
    const float* x  = (const float*)d_in[0];
    const float* p  = (const float*)d_in[1];
    const float* W1 = (const float*)d_in[2];
    const float* b1 = (const float*)d_in[3];
    const float* W2 = (const float*)d_in[4];
    const float* b2 = (const float*)d_in[5];
    float* y = (float*)d_out;

    dim3 grid(NB * BLOCKS_PER_B);   // 2048 blocks, 2/CU (70.7 KB LDS)
    dim3 block(TPB);
    hyperconv_kernel<<<grid, block, 0, stream>>>(x, p, W1, b1, W2, b2, y);
}